// Round 1
// baseline (323.633 us; speedup 1.0000x reference)
//
#include <hip/hip_runtime.h>

// Problem constants
#define NATOMS 20000
#define NCHAN  64
#define NIRR   16      // I
#define K2 120
#define K1 8
#define K0 4

// d_ws layout (floats):
//   [0 .. 262144)            W2[c][xyi]   c*4096 + ((x*16+y)*16+i)
//   [262144 .. 278528)       W1[c][xy]    c*256  + (x*16+y)
//   [278528 .. 279552)       W0[c][x]     c*16   + x
#define W2_ELEMS (NCHAN * NIRR * NIRR * NIRR)   // 262144
#define W1_ELEMS (NCHAN * NIRR * NIRR)          // 16384
#define W0_ELEMS (NCHAN * NIRR)                 // 1024
#define W1_OFF   W2_ELEMS
#define W0_OFF   (W2_ELEMS + W1_ELEMS)
#define TOTAL_W  (W2_ELEMS + W1_ELEMS + W0_ELEMS) // 279552

// ---------------------------------------------------------------------------
// Kernel 1: fold w2/w1/w0 into U2/U1/U0 -> per-channel tensors in d_ws.
// id maps 64 consecutive threads to the 64 channels of one (x,y,i) triple,
// so the U reads are wave-uniform (broadcast) and w reads are coalesced.
// ---------------------------------------------------------------------------
__global__ __launch_bounds__(256) void precompute_kernel(
    const float* __restrict__ U2, const float* __restrict__ U1,
    const float* __restrict__ U0, const float* __restrict__ w2,
    const float* __restrict__ w1, const float* __restrict__ w0,
    float* __restrict__ ws)
{
    int id = blockIdx.x * 256 + threadIdx.x;
    if (id < W2_ELEMS) {
        int c = id & 63;
        int xyi = id >> 6;
        const float* u = U2 + (size_t)xyi * K2;
        float acc = 0.f;
        #pragma unroll 8
        for (int k = 0; k < K2; ++k) acc += u[k] * w2[k * NCHAN + c];
        ws[c * 4096 + xyi] = acc;
    } else if (id < W0_OFF) {
        int id2 = id - W1_OFF;
        int c = id2 & 63;
        int xy = id2 >> 6;
        const float* u = U1 + xy * K1;
        float acc = 0.f;
        #pragma unroll
        for (int k = 0; k < K1; ++k) acc += u[k] * w1[k * NCHAN + c];
        ws[W1_OFF + c * 256 + xy] = acc;
    } else if (id < TOTAL_W) {
        int id3 = id - W0_OFF;
        int c = id3 & 63;
        int x = id3 >> 6;
        const float* u = U0 + x * K0;
        float acc = 0.f;
        #pragma unroll
        for (int k = 0; k < K0; ++k) acc += u[k] * w0[k * NCHAN + c];
        ws[W0_OFF + c * 16 + x] = acc;
    }
}

// ---------------------------------------------------------------------------
// Kernel 2: main contraction. One block = one channel c x 256 atoms.
// W2[c] (16 KB) staged in LDS; inner reads are wave-uniform float4 broadcasts
// (same address across all 64 lanes -> no bank conflicts).
// Per thread (one atom): 16 VGPRs of f, 16x(16x16 + 16 + 1) ~= 4.4K FMA.
// ---------------------------------------------------------------------------
__global__ __launch_bounds__(256) void contract_kernel(
    const float* __restrict__ nf,   // [N, C, 16]
    const float* __restrict__ ws,
    float* __restrict__ out)        // [N, C]
{
    __shared__ float W2s[4096];
    __shared__ float W1s[256];
    __shared__ float W0s[16];

    const int c   = blockIdx.y;
    const int tid = threadIdx.x;

    // stage per-channel tensors into LDS (coalesced)
    const float* w2p = ws + c * 4096;
    #pragma unroll
    for (int j = 0; j < 16; ++j) W2s[j * 256 + tid] = w2p[j * 256 + tid];
    W1s[tid] = ws[W1_OFF + c * 256 + tid];
    if (tid < 16) W0s[tid] = ws[W0_OFF + c * 16 + tid];
    __syncthreads();

    const int n = blockIdx.x * 256 + tid;
    if (n >= NATOMS) return;

    // load this atom/channel's 16 features into registers (4x float4)
    const float* fp = nf + ((size_t)n * NCHAN + c) * NIRR;
    float f[16];
    #pragma unroll
    for (int j = 0; j < 4; ++j) {
        float4 v = ((const float4*)fp)[j];
        f[4*j+0] = v.x; f[4*j+1] = v.y; f[4*j+2] = v.z; f[4*j+3] = v.w;
    }

    float o = 0.f;
    for (int x = 0; x < 16; ++x) {          // keep x as a loop (icache)
        float bx = 0.f;
        #pragma unroll
        for (int y = 0; y < 16; ++y) {      // 16 independent FMA chains (ILP)
            const int r = x * 16 + y;
            const float4* w = (const float4*)&W2s[r * 16];
            float a = 0.f;
            #pragma unroll
            for (int j = 0; j < 4; ++j) {
                float4 wv = w[j];           // ds_read_b128, wave-uniform
                a += wv.x * f[4*j+0] + wv.y * f[4*j+1]
                   + wv.z * f[4*j+2] + wv.w * f[4*j+3];
            }
            bx += (W1s[r] + a) * f[y];
        }
        o += (W0s[x] + bx) * f[x];
    }
    out[(size_t)n * NCHAN + c] = o;
}

extern "C" void kernel_launch(void* const* d_in, const int* in_sizes, int n_in,
                              void* d_out, int out_size, void* d_ws, size_t ws_size,
                              hipStream_t stream)
{
    const float* nf = (const float*)d_in[0];
    const float* U2 = (const float*)d_in[1];
    const float* U1 = (const float*)d_in[2];
    const float* U0 = (const float*)d_in[3];
    const float* w2 = (const float*)d_in[4];
    const float* w1 = (const float*)d_in[5];
    const float* w0 = (const float*)d_in[6];
    float* out = (float*)d_out;
    float* ws  = (float*)d_ws;

    // 1) fold weights into per-channel tensors (ws is re-poisoned each call)
    int pre_blocks = (TOTAL_W + 255) / 256;   // 1092
    precompute_kernel<<<pre_blocks, 256, 0, stream>>>(U2, U1, U0, w2, w1, w0, ws);

    // 2) main contraction: grid = (atom blocks, channels)
    dim3 grid((NATOMS + 255) / 256, NCHAN);   // (79, 64)
    contract_kernel<<<grid, 256, 0, stream>>>(nf, ws, out);
}

// Round 2
// 216.302 us; speedup vs baseline: 1.4962x; 1.4962x over previous
//
#include <hip/hip_runtime.h>

// Problem constants
#define NATOMS 20000
#define NCHAN  64
#define NIRR   16
#define K2 120
#define K1 8
#define K0 4

// ws layout (bytes):
//   [0 .. 524288)        W2bf  bf16[64][256][16]   c*4096 + xy*16 + i
//   [524288 .. 589824)   W1f   f32 [64][256]       c*256 + xy
//   [589824 .. 593920)   W0f   f32 [64][16]        c*16 + x
#define W2_ELEMS (NCHAN * 256 * 16)   // 262144
#define W1_ELEMS (NCHAN * 256)        // 16384
#define W0_ELEMS (NCHAN * 16)         // 1024
#define W1_BYTE_OFF 524288
#define W0_BYTE_OFF 589824
#define TOTAL_THREADS (W2_ELEMS + W1_ELEMS + W0_ELEMS)  // 279552

typedef __attribute__((ext_vector_type(8))) short bf16x8;
typedef __attribute__((ext_vector_type(4))) float f32x4;

__device__ inline short f2bf(float f) {
    union { float f; unsigned u; } v; v.f = f;
    unsigned r = v.u + 0x7FFF + ((v.u >> 16) & 1);   // RNE
    return (short)(r >> 16);
}

// ---------------------------------------------------------------------------
// Kernel 1: fold weights. id -> (c uniform per wave, xyi consecutive) so the
// w reads are wave-uniform scalar loads and the W2bf writes are coalesced.
// ---------------------------------------------------------------------------
__global__ __launch_bounds__(256) void precompute_kernel(
    const float* __restrict__ U2, const float* __restrict__ U1,
    const float* __restrict__ U0, const float* __restrict__ w2,
    const float* __restrict__ w1, const float* __restrict__ w0,
    void* __restrict__ wsv)
{
    short* W2bf = (short*)wsv;
    float* W1f  = (float*)((char*)wsv + W1_BYTE_OFF);
    float* W0f  = (float*)((char*)wsv + W0_BYTE_OFF);

    int id = blockIdx.x * 256 + threadIdx.x;
    if (id < W2_ELEMS) {
        int c = id >> 12, xyi = id & 4095;
        const float4* u = (const float4*)(U2 + (size_t)xyi * K2);
        float acc = 0.f;
        #pragma unroll
        for (int k4 = 0; k4 < K2 / 4; ++k4) {
            float4 uv = u[k4];
            acc += uv.x * w2[(k4*4+0)*NCHAN + c] + uv.y * w2[(k4*4+1)*NCHAN + c]
                 + uv.z * w2[(k4*4+2)*NCHAN + c] + uv.w * w2[(k4*4+3)*NCHAN + c];
        }
        W2bf[c * 4096 + xyi] = f2bf(acc);
    } else if (id < W2_ELEMS + W1_ELEMS) {
        int id2 = id - W2_ELEMS;
        int c = id2 >> 8, xy = id2 & 255;
        const float* u = U1 + xy * K1;
        float acc = 0.f;
        #pragma unroll
        for (int k = 0; k < K1; ++k) acc += u[k] * w1[k * NCHAN + c];
        W1f[c * 256 + xy] = acc;
    } else if (id < TOTAL_THREADS) {
        int id3 = id - W2_ELEMS - W1_ELEMS;
        int c = id3 >> 4, x = id3 & 15;
        const float* u = U0 + x * K0;
        float acc = 0.f;
        #pragma unroll
        for (int k = 0; k < K0; ++k) acc += u[k] * w0[k * NCHAN + c];
        W0f[c * 16 + x] = acc;
    }
}

// ---------------------------------------------------------------------------
// Kernel 2: fused MFMA contraction.
// Block = 1 channel x 64 atoms (4 waves x 16 atoms). Per wave:
//   A2[atom, xy] = sum_i W2bf[c,xy,i] * f_bf[atom,i]  via 16x mfma 16x16x32
//   (K padded 16->32 with zeros; C-operand preloaded with W1 -> exact fp32 add)
//   out[n,c]     = sum_col f[col] * ( sum_j acc_j * f[j] + W0[col] )
//   reduced over the 16 lanes (cols) by a width-16 butterfly.
// Verified gfx950 16x16x32 bf16 layouts (m89):
//   A: lane l, elem j -> A[m=l&15][k=(l>>4)*8+j]
//   B: lane l, elem j -> B[k=(l>>4)*8+j][n=l&15]
//   D: lane l, reg  r -> D[row=(l>>4)*4+r][col=l&15]
// ---------------------------------------------------------------------------
__global__ __launch_bounds__(256) void contract_kernel(
    const float* __restrict__ nf,   // [N, 64, 16]
    const void* __restrict__ wsv,
    float* __restrict__ out)        // [N, 64]
{
    const short* W2g = (const short*)wsv;
    const float* W1g = (const float*)((const char*)wsv + W1_BYTE_OFF);
    const float* W0g = (const float*)((const char*)wsv + W0_BYTE_OFF);

    __shared__ short W2s[4096];       // [xy][i] bf16, 8 KB
    __shared__ float W1s[256];        // [xy]
    __shared__ float W0s[16];         // [x]
    __shared__ float Fs[4][16][20];   // per-wave fp32 F tile [atom][i], pad 20

    const int c    = blockIdx.y;
    const int tid  = threadIdx.x;
    const int wave = tid >> 6;
    const int lane = tid & 63;
    const int m    = lane & 15;       // A-row / B-col / D-col
    const int q    = lane >> 4;       // quad 0..3

    // --- stage channel tensors (coalesced) ---
    {
        const uint4* src = (const uint4*)(W2g + (size_t)c * 4096);  // 512 uint4
        ((uint4*)W2s)[tid]       = src[tid];
        ((uint4*)W2s)[tid + 256] = src[tid + 256];
        W1s[tid] = W1g[c * 256 + tid];
        if (tid < 16) W0s[tid] = W0g[c * 16 + tid];
    }

    // --- load A fragment (16 atoms x 16 i, K padded to 32) + stage fp32 F ---
    const int atom0 = blockIdx.x * 64 + wave * 16;
    const int n_a   = atom0 + m;
    bf16x8 afrag = (bf16x8)0;
    if (q < 2) {
        float4 v0 = {0,0,0,0}, v1 = {0,0,0,0};
        if (n_a < NATOMS) {
            const float4* fp = (const float4*)(nf + ((size_t)n_a * NCHAN + c) * NIRR + q * 8);
            v0 = fp[0]; v1 = fp[1];
        }
        afrag[0] = f2bf(v0.x); afrag[1] = f2bf(v0.y);
        afrag[2] = f2bf(v0.z); afrag[3] = f2bf(v0.w);
        afrag[4] = f2bf(v1.x); afrag[5] = f2bf(v1.y);
        afrag[6] = f2bf(v1.z); afrag[7] = f2bf(v1.w);
        *(float4*)&Fs[wave][m][q * 8]     = v0;
        *(float4*)&Fs[wave][m][q * 8 + 4] = v1;
    }
    __syncthreads();

    // --- 16 MFMAs: acc_j[row=atom][col=y] = W1[x=j,y] + sum_i f[atom,i]*W2[x=j,y,i] ---
    f32x4 acc[16];
    #pragma unroll
    for (int j = 0; j < 16; ++j) {
        float w = W1s[j * 16 + m];            // broadcast within quad groups
        acc[j] = (f32x4){w, w, w, w};
    }
    #pragma unroll
    for (int j = 0; j < 16; ++j) {
        bf16x8 bfrag = (bf16x8)0;
        if (q < 2)
            bfrag = *(const bf16x8*)&W2s[(j * 16 + m) * 16 + q * 8];
        acc[j] = __builtin_amdgcn_mfma_f32_16x16x32_bf16(afrag, bfrag, acc[j], 0, 0, 0);
    }

    // --- epilogue: per lane, 4 atoms (rows q*4+r), col y = m ---
    float t[4];
    #pragma unroll
    for (int r = 0; r < 4; ++r) {
        const int a = q * 4 + r;              // atom row in D
        float4 f0 = *(const float4*)&Fs[wave][a][0];
        float4 f1 = *(const float4*)&Fs[wave][a][4];
        float4 f2 = *(const float4*)&Fs[wave][a][8];
        float4 f3 = *(const float4*)&Fs[wave][a][12];
        float fcol = Fs[wave][a][m];
        float s = 0.f;
        s += acc[ 0][r] * f0.x; s += acc[ 1][r] * f0.y;
        s += acc[ 2][r] * f0.z; s += acc[ 3][r] * f0.w;
        s += acc[ 4][r] * f1.x; s += acc[ 5][r] * f1.y;
        s += acc[ 6][r] * f1.z; s += acc[ 7][r] * f1.w;
        s += acc[ 8][r] * f2.x; s += acc[ 9][r] * f2.y;
        s += acc[10][r] * f2.z; s += acc[11][r] * f2.w;
        s += acc[12][r] * f3.x; s += acc[13][r] * f3.y;
        s += acc[14][r] * f3.z; s += acc[15][r] * f3.w;
        t[r] = fcol * (s + W0s[m]);
    }
    // butterfly sum over the 16 lanes (cols) of each quad group
    #pragma unroll
    for (int off = 1; off < 16; off <<= 1) {
        #pragma unroll
        for (int r = 0; r < 4; ++r)
            t[r] += __shfl_xor(t[r], off, 16);
    }
    if (m == 0) {
        #pragma unroll
        for (int r = 0; r < 4; ++r) {
            int n = atom0 + q * 4 + r;
            if (n < NATOMS) out[(size_t)n * NCHAN + c] = t[r];
        }
    }
}

extern "C" void kernel_launch(void* const* d_in, const int* in_sizes, int n_in,
                              void* d_out, int out_size, void* d_ws, size_t ws_size,
                              hipStream_t stream)
{
    const float* nf = (const float*)d_in[0];
    const float* U2 = (const float*)d_in[1];
    const float* U1 = (const float*)d_in[2];
    const float* U0 = (const float*)d_in[3];
    const float* w2 = (const float*)d_in[4];
    const float* w1 = (const float*)d_in[5];
    const float* w0 = (const float*)d_in[6];
    float* out = (float*)d_out;

    int pre_blocks = (TOTAL_THREADS + 255) / 256;   // 1092
    precompute_kernel<<<pre_blocks, 256, 0, stream>>>(U2, U1, U0, w2, w1, w0, d_ws);

    dim3 grid((NATOMS + 63) / 64, NCHAN);           // (313, 64)
    contract_kernel<<<grid, 256, 0, stream>>>(nf, d_ws, out);
}